// Round 3
// baseline (221.598 us; speedup 1.0000x reference)
//
#include <hip/hip_runtime.h>

typedef _Float16 f16;
typedef _Float16 f16x4 __attribute__((ext_vector_type(4)));
typedef _Float16 f16x8 __attribute__((ext_vector_type(8)));
typedef float f32x4 __attribute__((ext_vector_type(4)));

#define NB 8192
#define DIM 2048

// ---- workspace byte offsets (pack tables only; ~2.8 MB) ----
#define OFF_W1P    0u           // f32[256] (atomic, pre-zeroed)
#define OFF_WOP    1024u        // f32[128]
#define OFF_W1HP   2048u        // f16 [16 mt][64 kc][64 lane][8] = 1 MB
#define OFF_W1LP   1050624u     // 1 MB
#define OFF_WOTHP  2099200u     // f16 [8][64][64][8] = 512 KB
#define OFF_W2HP   2623488u     // f16 [8][8][64][8] = 64 KB
#define OFF_W2LP   2689024u     // 64 KB
#define OFF_W2THP  2754560u     // f16 [16][4][64][8] = 64 KB

__device__ __forceinline__ f16 hi16(float x) { return (f16)x; }
__device__ __forceinline__ f16 lo16(float x, f16 h) { return (f16)(x - (float)h); }

// ---------------- pack kernel: fragment-major fp16 hi/lo weights ----------------
// (layouts identical to validated round-2 packs)
__global__ void k_pack(const float* __restrict__ W1, const float* __restrict__ Wo,
                       const float* __restrict__ W2, f16* __restrict__ W1h,
                       f16* __restrict__ W1l, f16* __restrict__ WoTh,
                       f16* __restrict__ W2h, f16* __restrict__ W2l,
                       f16* __restrict__ W2Th) {
  int tid = blockIdx.x * 256 + threadIdx.x;   // 106496 total
  int g, c, kc, nt;
  if (tid < 65536) {                 // W1: KC=64, NT=16
    int cid = tid; int lane = cid & 63; int kcnt = cid >> 6;
    kc = kcnt & 63; nt = kcnt >> 6; g = lane >> 4; c = lane & 15;
    f16x8 h8, l8;
    #pragma unroll
    for (int j = 0; j < 8; ++j) {
      float v = W1[(size_t)(kc * 32 + 8 * g + j) * 256 + nt * 16 + c];
      f16 h = hi16(v); h8[j] = h; l8[j] = lo16(v, h);
    }
    *(f16x8*)&W1h[(size_t)cid * 8] = h8;
    *(f16x8*)&W1l[(size_t)cid * 8] = l8;
  } else if (tid < 98304) {          // WoT: KC=64, NT=8
    int cid = tid - 65536; int lane = cid & 63; int kcnt = cid >> 6;
    kc = kcnt & 63; nt = kcnt >> 6; g = lane >> 4; c = lane & 15;
    f16x8 h8;
    #pragma unroll
    for (int j = 0; j < 8; ++j)
      h8[j] = hi16(Wo[(size_t)(nt * 16 + c) * 2048 + kc * 32 + 8 * g + j]);
    *(f16x8*)&WoTh[(size_t)cid * 8] = h8;
  } else if (tid < 102400) {         // W2: KC=8, NT=8
    int cid = tid - 98304; int lane = cid & 63; int kcnt = cid >> 6;
    kc = kcnt & 7; nt = kcnt >> 3; g = lane >> 4; c = lane & 15;
    f16x8 h8, l8;
    #pragma unroll
    for (int j = 0; j < 8; ++j) {
      float v = W2[(size_t)(kc * 32 + 8 * g + j) * 128 + nt * 16 + c];
      f16 h = hi16(v); h8[j] = h; l8[j] = lo16(v, h);
    }
    *(f16x8*)&W2h[(size_t)cid * 8] = h8;
    *(f16x8*)&W2l[(size_t)cid * 8] = l8;
  } else if (tid < 106496) {         // W2T: KC=4, NT=16
    int cid = tid - 102400; int lane = cid & 63; int kcnt = cid >> 6;
    kc = kcnt & 3; nt = kcnt >> 2; g = lane >> 4; c = lane & 15;
    f16x8 h8;
    #pragma unroll
    for (int j = 0; j < 8; ++j)
      h8[j] = hi16(W2[(size_t)(nt * 16 + c) * 128 + kc * 32 + 8 * g + j]);
    *(f16x8*)&W2Th[(size_t)cid * 8] = h8;
  }
}

// w1p[i] = sum_d W1[d][i]*Wp[d]
__global__ void k_w1p(const float* __restrict__ W1, const float* __restrict__ Wp,
                      float* __restrict__ w1p) {
  int i = threadIdx.x; int d0 = blockIdx.x * 64;
  float acc = 0.f;
  #pragma unroll 8
  for (int dd = 0; dd < 64; ++dd)
    acc = fmaf(W1[(size_t)(d0 + dd) * 256 + i], Wp[d0 + dd], acc);
  atomicAdd(&w1p[i], acc);
}

// wop[j] = sum_d Wo[j][d]*Wp[d]
__global__ void k_wop(const float* __restrict__ Wo, const float* __restrict__ Wp,
                      float* __restrict__ wop) {
  int j = blockIdx.x; int t = threadIdx.x;
  float acc = 0.f;
  #pragma unroll
  for (int d = t; d < 2048; d += 256) acc = fmaf(Wo[(size_t)j * 2048 + d], Wp[d], acc);
  __shared__ float red[256];
  red[t] = acc; __syncthreads();
  for (int s = 128; s > 0; s >>= 1) { if (t < s) red[t] += red[t + s]; __syncthreads(); }
  if (t == 0) wop[j] = red[0];
}

// ---- swizzled f16-offsets (16B-octet XOR swizzle) ----
__device__ __forceinline__ int sw256(int row, int o) { return (row * 32 + (o ^ (row & 15))) * 8; }
__device__ __forceinline__ int sw128(int row, int o) { return (row * 16 + (o ^ (row & 15))) * 8; }

#define MFMA16(a, b, acc) __builtin_amdgcn_mfma_f32_16x16x32_f16(a, b, acc, 0, 0, 0)

// ---------------- fully-fused network kernel ----------------
// 256 blocks x 256 thr (4 waves). Block = 32 sample-rows, full K=2048.
// m-dim = feature cols, n-dim = sample rows throughout; each layer's C-layout
// feeds the next via swizzled-LDS [row][featcol] roundtrip; jx/jtx in-register.
__global__ __launch_bounds__(256) void k_fused(
    const float* __restrict__ X, const f16* __restrict__ W1h, const f16* __restrict__ W1l,
    const f16* __restrict__ WoTh, const f16* __restrict__ W2h, const f16* __restrict__ W2l,
    const f16* __restrict__ W2Th, const float* __restrict__ b1, const float* __restrict__ b2,
    const float* __restrict__ wop, const float* __restrict__ w1p, const float* __restrict__ bp,
    float* __restrict__ OUT) {
  __shared__ __align__(16) char smem[57472];
  f16* XH = (f16*)smem;              // 16KB: X-hi, later H1h
  f16* XL = (f16*)(smem + 16384);    // 16KB: X-lo, later H1l
  f16* DH = (f16*)(smem + 32768);    // 16KB: dh1
  f16* GA = (f16*)(smem + 49152);    // 8KB: ga2
  float* outr = (float*)(smem + 57344);

  const int tid = threadIdx.x;
  const int w = tid >> 6, lane = tid & 63;
  const int g = lane >> 4, c = lane & 15;
  const int m0 = blockIdx.x * 32;

  if (tid < 32) outr[tid] = 0.f;

  f32x4 accW[4][2], accG[2][2];
  #pragma unroll
  for (int m = 0; m < 4; ++m)
    #pragma unroll
    for (int nt = 0; nt < 2; ++nt) accW[m][nt] = (f32x4)0.f;
  #pragma unroll
  for (int m = 0; m < 2; ++m)
    #pragma unroll
    for (int nt = 0; nt < 2; ++nt) accG[m][nt] = (f32x4)0.f;

  // X prefetch: thread owns 32 consecutive k of one row per sc-chunk
  const int xrow = tid >> 3, xseg = tid & 7;
  const float4* xbase = (const float4*)(X + (size_t)(m0 + xrow) * DIM + xseg * 32);
  float4 xr[8];
  #pragma unroll
  for (int i = 0; i < 8; ++i) xr[i] = xbase[i];

  // ================= Layer 1: pre1 = z@W1 (3-pass split), gh2 = z@WoT =================
  for (int sc = 0; sc < 8; ++sc) {
    __syncthreads();                       // prior-chunk LDS reads complete
    #pragma unroll
    for (int i = 0; i < 4; ++i) {          // cvt + stage (T14 write-late)
      float q[8] = {xr[2*i].x, xr[2*i].y, xr[2*i].z, xr[2*i].w,
                    xr[2*i+1].x, xr[2*i+1].y, xr[2*i+1].z, xr[2*i+1].w};
      f16x8 h8, l8;
      #pragma unroll
      for (int j = 0; j < 8; ++j) { f16 h = hi16(q[j]); h8[j] = h; l8[j] = lo16(q[j], h); }
      int a = sw256(xrow, xseg * 4 + i);
      *(f16x8*)&XH[a] = h8;
      *(f16x8*)&XL[a] = l8;
    }
    __syncthreads();
    if (sc < 7) {                          // T14 issue-early: next chunk under compute
      #pragma unroll
      for (int i = 0; i < 8; ++i) xr[i] = xbase[(sc + 1) * 64 + i];
    }
    const size_t kb = (size_t)sc * 8;
    #pragma unroll
    for (int kc8 = 0; kc8 < 8; ++kc8) {
      const size_t kcg = kb + kc8;
      f16x8 whf[4], wlf[4], wof[2], bh[2], bl[2];
      #pragma unroll
      for (int m = 0; m < 4; ++m) {
        size_t idx = (((size_t)(w * 4 + m) * 64 + kcg) * 64 + lane) * 8;
        whf[m] = *(const f16x8*)&W1h[idx];
        wlf[m] = *(const f16x8*)&W1l[idx];
      }
      #pragma unroll
      for (int m = 0; m < 2; ++m) {
        size_t idx = (((size_t)(w * 2 + m) * 64 + kcg) * 64 + lane) * 8;
        wof[m] = *(const f16x8*)&WoTh[idx];
      }
      #pragma unroll
      for (int nt = 0; nt < 2; ++nt) {
        int a = sw256(nt * 16 + c, kc8 * 4 + g);
        bh[nt] = *(const f16x8*)&XH[a];
        bl[nt] = *(const f16x8*)&XL[a];
      }
      #pragma unroll
      for (int m = 0; m < 4; ++m)
        #pragma unroll
        for (int nt = 0; nt < 2; ++nt) {
          accW[m][nt] = MFMA16(whf[m], bh[nt], accW[m][nt]);
          accW[m][nt] = MFMA16(whf[m], bl[nt], accW[m][nt]);
          accW[m][nt] = MFMA16(wlf[m], bh[nt], accW[m][nt]);
        }
      #pragma unroll
      for (int m = 0; m < 2; ++m)
        #pragma unroll
        for (int nt = 0; nt < 2; ++nt)
          accG[m][nt] = MFMA16(wof[m], bh[nt], accG[m][nt]);
    }
  }
  __syncthreads();   // all L1 LDS reads done before overwriting X region with H1

  // ================= h1 / dh1 / mask1 -> LDS =================
  unsigned mask1 = 0;
  #pragma unroll
  for (int m = 0; m < 4; ++m) {
    float4 b1f = *(const float4*)&b1[w * 64 + m * 16 + 4 * g];
    float b1a[4] = {b1f.x, b1f.y, b1f.z, b1f.w};
    #pragma unroll
    for (int nt = 0; nt < 2; ++nt) {
      f16x4 hh, hl, hd;
      #pragma unroll
      for (int rr = 0; rr < 4; ++rr) {
        float pre = accW[m][nt][rr];
        float a1 = pre + b1a[rr];
        bool mk = a1 > 0.f;
        float h1 = mk ? a1 : 0.f;
        f16 h = hi16(h1);
        hh[rr] = h; hl[rr] = lo16(h1, h);
        hd[rr] = mk ? hi16(pre) : (f16)0.f;
        mask1 |= (unsigned)mk << (m * 8 + nt * 4 + rr);
      }
      int row = nt * 16 + c;
      int o = w * 8 + m * 2 + (g >> 1);
      int a = sw256(row, o) + (g & 1) * 4;
      *(f16x4*)&XH[a] = hh;   // H1h
      *(f16x4*)&XL[a] = hl;   // H1l
      *(f16x4*)&DH[a] = hd;
    }
  }
  __syncthreads();

  // ================= Layer 2: a2 = h1@W2 (3-pass) [+b2->mask2], da2 = dh1@W2h =================
  f32x4 acc2[2][2], accD[2][2];
  #pragma unroll
  for (int m = 0; m < 2; ++m)
    #pragma unroll
    for (int nt = 0; nt < 2; ++nt) { acc2[m][nt] = (f32x4)0.f; accD[m][nt] = (f32x4)0.f; }
  #pragma unroll
  for (int kc = 0; kc < 8; ++kc) {
    f16x8 w2hf[2], w2lf[2], bhh[2], bhl[2], bdh[2];
    #pragma unroll
    for (int m = 0; m < 2; ++m) {
      size_t idx = (((size_t)(w * 2 + m) * 8 + kc) * 64 + lane) * 8;
      w2hf[m] = *(const f16x8*)&W2h[idx];
      w2lf[m] = *(const f16x8*)&W2l[idx];
    }
    #pragma unroll
    for (int nt = 0; nt < 2; ++nt) {
      int a = sw256(nt * 16 + c, kc * 4 + g);
      bhh[nt] = *(const f16x8*)&XH[a];
      bhl[nt] = *(const f16x8*)&XL[a];
      bdh[nt] = *(const f16x8*)&DH[a];
    }
    #pragma unroll
    for (int m = 0; m < 2; ++m)
      #pragma unroll
      for (int nt = 0; nt < 2; ++nt) {
        acc2[m][nt] = MFMA16(w2hf[m], bhh[nt], acc2[m][nt]);
        acc2[m][nt] = MFMA16(w2hf[m], bhl[nt], acc2[m][nt]);
        acc2[m][nt] = MFMA16(w2lf[m], bhh[nt], acc2[m][nt]);
        accD[m][nt] = MFMA16(w2hf[m], bdh[nt], accD[m][nt]);
      }
  }
  // epilogue: mask2, jx partial, ga2 -> LDS
  float jxv[2] = {0.f, 0.f};
  #pragma unroll
  for (int m = 0; m < 2; ++m) {
    float4 b2f = *(const float4*)&b2[w * 32 + m * 16 + 4 * g];
    float4 wpf = *(const float4*)&wop[w * 32 + m * 16 + 4 * g];
    float b2a[4] = {b2f.x, b2f.y, b2f.z, b2f.w};
    float wpa[4] = {wpf.x, wpf.y, wpf.z, wpf.w};
    #pragma unroll
    for (int nt = 0; nt < 2; ++nt) {
      f16x4 gav;
      #pragma unroll
      for (int rr = 0; rr < 4; ++rr) {
        float a2v = acc2[m][nt][rr] + b2a[rr];
        bool m2 = a2v > 0.f;
        gav[rr] = m2 ? hi16(accG[m][nt][rr]) : (f16)0.f;
        if (m2) jxv[nt] = fmaf(accD[m][nt][rr], wpa[rr], jxv[nt]);
      }
      int row = nt * 16 + c;
      int o = w * 4 + m * 2 + (g >> 1);
      int a = sw128(row, o) + (g & 1) * 4;
      *(f16x4*)&GA[a] = gav;
    }
  }
  __syncthreads();

  // ================= Layer 3: gh1 = ga2@W2T; jtx in-register =================
  f32x4 acc3[4][2];
  #pragma unroll
  for (int m = 0; m < 4; ++m)
    #pragma unroll
    for (int nt = 0; nt < 2; ++nt) acc3[m][nt] = (f32x4)0.f;
  #pragma unroll
  for (int kc = 0; kc < 4; ++kc) {
    f16x8 w2tf[4], bga[2];
    #pragma unroll
    for (int m = 0; m < 4; ++m) {
      size_t idx = (((size_t)(w * 4 + m) * 4 + kc) * 64 + lane) * 8;
      w2tf[m] = *(const f16x8*)&W2Th[idx];
    }
    #pragma unroll
    for (int nt = 0; nt < 2; ++nt) {
      int a = sw128(nt * 16 + c, kc * 4 + g);
      bga[nt] = *(const f16x8*)&GA[a];
    }
    #pragma unroll
    for (int m = 0; m < 4; ++m)
      #pragma unroll
      for (int nt = 0; nt < 2; ++nt)
        acc3[m][nt] = MFMA16(w2tf[m], bga[nt], acc3[m][nt]);
  }
  float jtv[2] = {0.f, 0.f};
  #pragma unroll
  for (int m = 0; m < 4; ++m) {
    float4 wpf = *(const float4*)&w1p[w * 64 + m * 16 + 4 * g];
    float wpa[4] = {wpf.x, wpf.y, wpf.z, wpf.w};
    #pragma unroll
    for (int nt = 0; nt < 2; ++nt)
      #pragma unroll
      for (int rr = 0; rr < 4; ++rr)
        if ((mask1 >> (m * 8 + nt * 4 + rr)) & 1)
          jtv[nt] = fmaf(acc3[m][nt][rr], wpa[rr], jtv[nt]);
  }
  float s0 = jxv[0] - jtv[0];
  float s1 = jxv[1] - jtv[1];
  s0 += __shfl_xor(s0, 16, 64); s0 += __shfl_xor(s0, 32, 64);
  s1 += __shfl_xor(s1, 16, 64); s1 += __shfl_xor(s1, 32, 64);
  if (lane < 16) {
    atomicAdd(&outr[lane], s0);
    atomicAdd(&outr[16 + lane], s1);
  }
  __syncthreads();
  if (tid < 32) OUT[m0 + tid] = outr[tid] + bp[0];
}

extern "C" void kernel_launch(void* const* d_in, const int* in_sizes, int n_in,
                              void* d_out, int out_size, void* d_ws, size_t ws_size,
                              hipStream_t stream) {
  (void)in_sizes; (void)n_in; (void)out_size; (void)ws_size;
  const float* x  = (const float*)d_in[0];
  const float* W1 = (const float*)d_in[1];
  const float* b1 = (const float*)d_in[2];
  const float* W2 = (const float*)d_in[3];
  const float* b2 = (const float*)d_in[4];
  const float* Wo = (const float*)d_in[5];
  // d_in[6] = bo: drops out of both jvp and vjp
  const float* Wp = (const float*)d_in[7];
  const float* bp = (const float*)d_in[8];
  char* ws = (char*)d_ws;
  float* OUT = (float*)d_out;

  float* w1p = (float*)(ws + OFF_W1P);
  float* wop = (float*)(ws + OFF_WOP);
  f16* W1hP  = (f16*)(ws + OFF_W1HP);
  f16* W1lP  = (f16*)(ws + OFF_W1LP);
  f16* WoThP = (f16*)(ws + OFF_WOTHP);
  f16* W2hP  = (f16*)(ws + OFF_W2HP);
  f16* W2lP  = (f16*)(ws + OFF_W2LP);
  f16* W2ThP = (f16*)(ws + OFF_W2THP);

  hipMemsetAsync(ws + OFF_W1P, 0, 1024, stream);
  k_pack<<<416, 256, 0, stream>>>(W1, Wo, W2, W1hP, W1lP, WoThP, W2hP, W2lP, W2ThP);
  k_w1p<<<32, 256, 0, stream>>>(W1, Wp, w1p);
  k_wop<<<128, 256, 0, stream>>>(Wo, Wp, wop);
  k_fused<<<256, 256, 0, stream>>>(x, W1hP, W1lP, WoThP, W2hP, W2lP, W2ThP,
                                   b1, b2, wop, w1p, bp, OUT);
}

// Round 4
// 154.565 us; speedup vs baseline: 1.4337x; 1.4337x over previous
//
#include <hip/hip_runtime.h>

typedef _Float16 f16;
typedef _Float16 f16x4 __attribute__((ext_vector_type(4)));
typedef _Float16 f16x8 __attribute__((ext_vector_type(8)));
typedef float f32x4 __attribute__((ext_vector_type(4)));

#define NB 8192
#define DIM 2048

// ---- workspace byte offsets (pack tables only; ~2.8 MB) ----
#define OFF_W1P    0u           // f32[256] (atomic, pre-zeroed)
#define OFF_WOP    1024u        // f32[128]
#define OFF_W1HP   2048u        // f16 [16 mt][64 kc][64 lane][8] = 1 MB
#define OFF_W1LP   1050624u     // 1 MB
#define OFF_WOTHP  2099200u     // f16 [8][64][64][8] = 512 KB
#define OFF_W2HP   2623488u     // f16 [8][8][64][8] = 64 KB
#define OFF_W2LP   2689024u     // 64 KB
#define OFF_W2THP  2754560u     // f16 [16][4][64][8] = 64 KB

__device__ __forceinline__ f16 hi16(float x) { return (f16)x; }
__device__ __forceinline__ f16 lo16(float x, f16 h) { return (f16)(x - (float)h); }

// ---------------- pack kernel: fragment-major fp16 hi/lo weights ----------------
// (layouts identical to validated round-2/3 packs)
__global__ void k_pack(const float* __restrict__ W1, const float* __restrict__ Wo,
                       const float* __restrict__ W2, f16* __restrict__ W1h,
                       f16* __restrict__ W1l, f16* __restrict__ WoTh,
                       f16* __restrict__ W2h, f16* __restrict__ W2l,
                       f16* __restrict__ W2Th) {
  int tid = blockIdx.x * 256 + threadIdx.x;   // 106496 total
  int g, c, kc, nt;
  if (tid < 65536) {                 // W1: KC=64, NT=16
    int cid = tid; int lane = cid & 63; int kcnt = cid >> 6;
    kc = kcnt & 63; nt = kcnt >> 6; g = lane >> 4; c = lane & 15;
    f16x8 h8, l8;
    #pragma unroll
    for (int j = 0; j < 8; ++j) {
      float v = W1[(size_t)(kc * 32 + 8 * g + j) * 256 + nt * 16 + c];
      f16 h = hi16(v); h8[j] = h; l8[j] = lo16(v, h);
    }
    *(f16x8*)&W1h[(size_t)cid * 8] = h8;
    *(f16x8*)&W1l[(size_t)cid * 8] = l8;
  } else if (tid < 98304) {          // WoT: KC=64, NT=8
    int cid = tid - 65536; int lane = cid & 63; int kcnt = cid >> 6;
    kc = kcnt & 63; nt = kcnt >> 6; g = lane >> 4; c = lane & 15;
    f16x8 h8;
    #pragma unroll
    for (int j = 0; j < 8; ++j)
      h8[j] = hi16(Wo[(size_t)(nt * 16 + c) * 2048 + kc * 32 + 8 * g + j]);
    *(f16x8*)&WoTh[(size_t)cid * 8] = h8;
  } else if (tid < 102400) {         // W2: KC=8, NT=8
    int cid = tid - 98304; int lane = cid & 63; int kcnt = cid >> 6;
    kc = kcnt & 7; nt = kcnt >> 3; g = lane >> 4; c = lane & 15;
    f16x8 h8, l8;
    #pragma unroll
    for (int j = 0; j < 8; ++j) {
      float v = W2[(size_t)(kc * 32 + 8 * g + j) * 128 + nt * 16 + c];
      f16 h = hi16(v); h8[j] = h; l8[j] = lo16(v, h);
    }
    *(f16x8*)&W2h[(size_t)cid * 8] = h8;
    *(f16x8*)&W2l[(size_t)cid * 8] = l8;
  } else if (tid < 106496) {         // W2T: KC=4, NT=16
    int cid = tid - 102400; int lane = cid & 63; int kcnt = cid >> 6;
    kc = kcnt & 3; nt = kcnt >> 2; g = lane >> 4; c = lane & 15;
    f16x8 h8;
    #pragma unroll
    for (int j = 0; j < 8; ++j)
      h8[j] = hi16(W2[(size_t)(nt * 16 + c) * 128 + kc * 32 + 8 * g + j]);
    *(f16x8*)&W2Th[(size_t)cid * 8] = h8;
  }
}

// w1p[i] = sum_d W1[d][i]*Wp[d]
__global__ void k_w1p(const float* __restrict__ W1, const float* __restrict__ Wp,
                      float* __restrict__ w1p) {
  int i = threadIdx.x; int d0 = blockIdx.x * 64;
  float acc = 0.f;
  #pragma unroll 8
  for (int dd = 0; dd < 64; ++dd)
    acc = fmaf(W1[(size_t)(d0 + dd) * 256 + i], Wp[d0 + dd], acc);
  atomicAdd(&w1p[i], acc);
}

// wop[j] = sum_d Wo[j][d]*Wp[d]
__global__ void k_wop(const float* __restrict__ Wo, const float* __restrict__ Wp,
                      float* __restrict__ wop) {
  int j = blockIdx.x; int t = threadIdx.x;
  float acc = 0.f;
  #pragma unroll
  for (int d = t; d < 2048; d += 256) acc = fmaf(Wo[(size_t)j * 2048 + d], Wp[d], acc);
  __shared__ float red[256];
  red[t] = acc; __syncthreads();
  for (int s = 128; s > 0; s >>= 1) { if (t < s) red[t] += red[t + s]; __syncthreads(); }
  if (t == 0) wop[j] = red[0];
}

// ---- swizzled f16-offsets (16B-octet XOR swizzle) ----
__device__ __forceinline__ int sw256(int row, int o) { return (row * 32 + (o ^ (row & 15))) * 8; }
__device__ __forceinline__ int sw128(int row, int o) { return (row * 16 + (o ^ (row & 15))) * 8; }

#define MFMA16(a, b, acc) __builtin_amdgcn_mfma_f32_16x16x32_f16(a, b, acc, 0, 0, 0)

// ---------------- fully-fused network kernel ----------------
// 256 blocks x 512 thr (8 waves, 2 waves/SIMD). Block = 32 sample-rows, K=2048.
// m-dim = feature cols (split across 8 waves), n-dim = sample rows; each layer's
// C-layout feeds the next via swizzled-LDS roundtrip; jx/jtx in-register.
__global__ __launch_bounds__(512, 2) void k_fused(
    const float* __restrict__ X, const f16* __restrict__ W1h, const f16* __restrict__ W1l,
    const f16* __restrict__ WoTh, const f16* __restrict__ W2h, const f16* __restrict__ W2l,
    const f16* __restrict__ W2Th, const float* __restrict__ b1, const float* __restrict__ b2,
    const float* __restrict__ wop, const float* __restrict__ w1p, const float* __restrict__ bp,
    float* __restrict__ OUT) {
  __shared__ __align__(16) char smem[57472];
  f16* XH = (f16*)smem;              // 16KB: X-hi, later H1h
  f16* XL = (f16*)(smem + 16384);    // 16KB: X-lo, later H1l
  f16* DH = (f16*)(smem + 32768);    // 16KB: dh1
  f16* GA = (f16*)(smem + 49152);    // 8KB: ga2
  float* outr = (float*)(smem + 57344);

  const int tid = threadIdx.x;
  const int w = tid >> 6, lane = tid & 63;
  const int g = lane >> 4, c = lane & 15;
  const int m0 = blockIdx.x * 32;

  if (tid < 32) outr[tid] = 0.f;

  f32x4 accW[2][2], accG[2];
  #pragma unroll
  for (int m = 0; m < 2; ++m)
    #pragma unroll
    for (int nt = 0; nt < 2; ++nt) accW[m][nt] = (f32x4)0.f;
  #pragma unroll
  for (int nt = 0; nt < 2; ++nt) accG[nt] = (f32x4)0.f;

  // X prefetch: thread owns 16 consecutive k of one row per sc-chunk
  const int xrow = tid >> 4, xseg = tid & 15;
  const float4* xbase = (const float4*)(X + (size_t)(m0 + xrow) * DIM);
  float4 xr[4];
  #pragma unroll
  for (int i = 0; i < 4; ++i) xr[i] = xbase[xseg * 4 + i];

  // weight-fragment double buffers (depth-1.5 prefetch)
  f16x8 whA[2], wlA[2], woA, whB[2], wlB[2], woB;
#define LOADW(WH, WL, WO, KCG)                                              \
  {                                                                         \
    size_t kcg_ = (KCG);                                                    \
    _Pragma("unroll")                                                       \
    for (int m_ = 0; m_ < 2; ++m_) {                                        \
      size_t idx = (((size_t)(w * 2 + m_) * 64 + kcg_) * 64 + lane) * 8;    \
      WH[m_] = *(const f16x8*)&W1h[idx];                                    \
      WL[m_] = *(const f16x8*)&W1l[idx];                                    \
    }                                                                       \
    WO = *(const f16x8*)&WoTh[(((size_t)w * 64 + kcg_) * 64 + lane) * 8];   \
  }
#define L1MFMA(WH, WL, WO, KC8)                                             \
  {                                                                         \
    f16x8 bh[2], bl[2];                                                     \
    _Pragma("unroll")                                                       \
    for (int nt = 0; nt < 2; ++nt) {                                        \
      int a = sw256(nt * 16 + c, (KC8) * 4 + g);                            \
      bh[nt] = *(const f16x8*)&XH[a];                                       \
      bl[nt] = *(const f16x8*)&XL[a];                                       \
    }                                                                       \
    __builtin_amdgcn_s_setprio(1);                                          \
    _Pragma("unroll")                                                       \
    for (int m = 0; m < 2; ++m)                                             \
      _Pragma("unroll")                                                     \
      for (int nt = 0; nt < 2; ++nt) {                                      \
        accW[m][nt] = MFMA16(WH[m], bh[nt], accW[m][nt]);                   \
        accW[m][nt] = MFMA16(WH[m], bl[nt], accW[m][nt]);                   \
        accW[m][nt] = MFMA16(WL[m], bh[nt], accW[m][nt]);                   \
      }                                                                     \
    _Pragma("unroll")                                                       \
    for (int nt = 0; nt < 2; ++nt)                                          \
      accG[nt] = MFMA16(WO, bh[nt], accG[nt]);                              \
    __builtin_amdgcn_s_setprio(0);                                          \
  }

  // ================= Layer 1: pre1 = z@W1 (3-pass split), gh2 = z@WoT =================
  for (int sc = 0; sc < 8; ++sc) {
    __syncthreads();                       // prior-chunk LDS reads complete
    #pragma unroll
    for (int i = 0; i < 2; ++i) {          // cvt + stage
      float q[8] = {xr[2*i].x, xr[2*i].y, xr[2*i].z, xr[2*i].w,
                    xr[2*i+1].x, xr[2*i+1].y, xr[2*i+1].z, xr[2*i+1].w};
      f16x8 h8, l8;
      #pragma unroll
      for (int j = 0; j < 8; ++j) { f16 h = hi16(q[j]); h8[j] = h; l8[j] = lo16(q[j], h); }
      int a = sw256(xrow, xseg * 2 + i);
      *(f16x8*)&XH[a] = h8;
      *(f16x8*)&XL[a] = l8;
    }
    __syncthreads();
    if (sc < 7) {                          // issue next X chunk early
      #pragma unroll
      for (int i = 0; i < 4; ++i) xr[i] = xbase[(sc + 1) * 64 + xseg * 4 + i];
    }
    const size_t kb = (size_t)sc * 8;
    LOADW(whA, wlA, woA, kb + 0);
    #pragma unroll
    for (int kc2 = 0; kc2 < 8; kc2 += 2) {
      LOADW(whB, wlB, woB, kb + kc2 + 1);
      L1MFMA(whA, wlA, woA, kc2);
      if (kc2 + 2 < 8) LOADW(whA, wlA, woA, kb + kc2 + 2);
      L1MFMA(whB, wlB, woB, kc2 + 1);
    }
  }
  __syncthreads();   // all L1 LDS reads done before overwriting X region with H1

  // ================= h1 / dh1 / mask1 -> LDS =================
  unsigned mask1 = 0;
  #pragma unroll
  for (int m = 0; m < 2; ++m) {
    float4 b1f = *(const float4*)&b1[(w * 2 + m) * 16 + 4 * g];
    float b1a[4] = {b1f.x, b1f.y, b1f.z, b1f.w};
    #pragma unroll
    for (int nt = 0; nt < 2; ++nt) {
      f16x4 hh, hl, hd;
      #pragma unroll
      for (int rr = 0; rr < 4; ++rr) {
        float pre = accW[m][nt][rr];
        float a1 = pre + b1a[rr];
        bool mk = a1 > 0.f;
        float h1 = mk ? a1 : 0.f;
        f16 h = hi16(h1);
        hh[rr] = h; hl[rr] = lo16(h1, h);
        hd[rr] = mk ? hi16(pre) : (f16)0.f;
        mask1 |= (unsigned)mk << (m * 8 + nt * 4 + rr);
      }
      int row = nt * 16 + c;
      int o = w * 4 + m * 2 + (g >> 1);
      int a = sw256(row, o) + (g & 1) * 4;
      *(f16x4*)&XH[a] = hh;   // H1h
      *(f16x4*)&XL[a] = hl;   // H1l
      *(f16x4*)&DH[a] = hd;
    }
  }
  __syncthreads();

  // ================= Layer 2: a2 = h1@W2 (3-pass) [+b2->mask2], da2 = dh1@W2h =================
  f32x4 acc2[2], accD[2];
  #pragma unroll
  for (int nt = 0; nt < 2; ++nt) { acc2[nt] = (f32x4)0.f; accD[nt] = (f32x4)0.f; }
  #pragma unroll
  for (int kc = 0; kc < 8; ++kc) {
    f16x8 w2hf, w2lf, bhh[2], bhl[2], bdh[2];
    {
      size_t idx = (((size_t)w * 8 + kc) * 64 + lane) * 8;
      w2hf = *(const f16x8*)&W2h[idx];
      w2lf = *(const f16x8*)&W2l[idx];
    }
    #pragma unroll
    for (int nt = 0; nt < 2; ++nt) {
      int a = sw256(nt * 16 + c, kc * 4 + g);
      bhh[nt] = *(const f16x8*)&XH[a];
      bhl[nt] = *(const f16x8*)&XL[a];
      bdh[nt] = *(const f16x8*)&DH[a];
    }
    __builtin_amdgcn_s_setprio(1);
    #pragma unroll
    for (int nt = 0; nt < 2; ++nt) {
      acc2[nt] = MFMA16(w2hf, bhh[nt], acc2[nt]);
      acc2[nt] = MFMA16(w2hf, bhl[nt], acc2[nt]);
      acc2[nt] = MFMA16(w2lf, bhh[nt], acc2[nt]);
      accD[nt] = MFMA16(w2hf, bdh[nt], accD[nt]);
    }
    __builtin_amdgcn_s_setprio(0);
  }
  // epilogue: mask2, jx partial, ga2 -> LDS
  float jxv[2] = {0.f, 0.f};
  {
    float4 b2f = *(const float4*)&b2[w * 16 + 4 * g];
    float4 wpf = *(const float4*)&wop[w * 16 + 4 * g];
    float b2a[4] = {b2f.x, b2f.y, b2f.z, b2f.w};
    float wpa[4] = {wpf.x, wpf.y, wpf.z, wpf.w};
    #pragma unroll
    for (int nt = 0; nt < 2; ++nt) {
      f16x4 gav;
      #pragma unroll
      for (int rr = 0; rr < 4; ++rr) {
        float a2v = acc2[nt][rr] + b2a[rr];
        bool m2 = a2v > 0.f;
        gav[rr] = m2 ? hi16(accG[nt][rr]) : (f16)0.f;
        if (m2) jxv[nt] = fmaf(accD[nt][rr], wpa[rr], jxv[nt]);
      }
      int row = nt * 16 + c;
      int o = w * 2 + (g >> 1);
      int a = sw128(row, o) + (g & 1) * 4;
      *(f16x4*)&GA[a] = gav;
    }
  }
  __syncthreads();

  // ================= Layer 3: gh1 = ga2@W2T; jtx in-register =================
  f32x4 acc3[2][2];
  #pragma unroll
  for (int m = 0; m < 2; ++m)
    #pragma unroll
    for (int nt = 0; nt < 2; ++nt) acc3[m][nt] = (f32x4)0.f;
  #pragma unroll
  for (int kc = 0; kc < 4; ++kc) {
    f16x8 w2tf[2], bga[2];
    #pragma unroll
    for (int m = 0; m < 2; ++m) {
      size_t idx = (((size_t)(w * 2 + m) * 4 + kc) * 64 + lane) * 8;
      w2tf[m] = *(const f16x8*)&W2Th[idx];
    }
    #pragma unroll
    for (int nt = 0; nt < 2; ++nt) {
      int a = sw128(nt * 16 + c, kc * 4 + g);
      bga[nt] = *(const f16x8*)&GA[a];
    }
    __builtin_amdgcn_s_setprio(1);
    #pragma unroll
    for (int m = 0; m < 2; ++m)
      #pragma unroll
      for (int nt = 0; nt < 2; ++nt)
        acc3[m][nt] = MFMA16(w2tf[m], bga[nt], acc3[m][nt]);
    __builtin_amdgcn_s_setprio(0);
  }
  float jtv[2] = {0.f, 0.f};
  #pragma unroll
  for (int m = 0; m < 2; ++m) {
    float4 wpf = *(const float4*)&w1p[(w * 2 + m) * 16 + 4 * g];
    float wpa[4] = {wpf.x, wpf.y, wpf.z, wpf.w};
    #pragma unroll
    for (int nt = 0; nt < 2; ++nt)
      #pragma unroll
      for (int rr = 0; rr < 4; ++rr)
        if ((mask1 >> (m * 8 + nt * 4 + rr)) & 1)
          jtv[nt] = fmaf(acc3[m][nt][rr], wpa[rr], jtv[nt]);
  }
  float s0 = jxv[0] - jtv[0];
  float s1 = jxv[1] - jtv[1];
  s0 += __shfl_xor(s0, 16, 64); s0 += __shfl_xor(s0, 32, 64);
  s1 += __shfl_xor(s1, 16, 64); s1 += __shfl_xor(s1, 32, 64);
  if (lane < 16) {
    atomicAdd(&outr[lane], s0);
    atomicAdd(&outr[16 + lane], s1);
  }
  __syncthreads();
  if (tid < 32) OUT[m0 + tid] = outr[tid] + bp[0];
}

extern "C" void kernel_launch(void* const* d_in, const int* in_sizes, int n_in,
                              void* d_out, int out_size, void* d_ws, size_t ws_size,
                              hipStream_t stream) {
  (void)in_sizes; (void)n_in; (void)out_size; (void)ws_size;
  const float* x  = (const float*)d_in[0];
  const float* W1 = (const float*)d_in[1];
  const float* b1 = (const float*)d_in[2];
  const float* W2 = (const float*)d_in[3];
  const float* b2 = (const float*)d_in[4];
  const float* Wo = (const float*)d_in[5];
  // d_in[6] = bo: drops out of both jvp and vjp
  const float* Wp = (const float*)d_in[7];
  const float* bp = (const float*)d_in[8];
  char* ws = (char*)d_ws;
  float* OUT = (float*)d_out;

  float* w1p = (float*)(ws + OFF_W1P);
  float* wop = (float*)(ws + OFF_WOP);
  f16* W1hP  = (f16*)(ws + OFF_W1HP);
  f16* W1lP  = (f16*)(ws + OFF_W1LP);
  f16* WoThP = (f16*)(ws + OFF_WOTHP);
  f16* W2hP  = (f16*)(ws + OFF_W2HP);
  f16* W2lP  = (f16*)(ws + OFF_W2LP);
  f16* W2ThP = (f16*)(ws + OFF_W2THP);

  hipMemsetAsync(ws + OFF_W1P, 0, 1024, stream);
  k_pack<<<416, 256, 0, stream>>>(W1, Wo, W2, W1hP, W1lP, WoThP, W2hP, W2lP, W2ThP);
  k_w1p<<<32, 256, 0, stream>>>(W1, Wp, w1p);
  k_wop<<<128, 256, 0, stream>>>(Wo, Wp, wop);
  k_fused<<<256, 512, 0, stream>>>(x, W1hP, W1lP, WoThP, W2hP, W2lP, W2ThP,
                                   b1, b2, wop, w1p, bp, OUT);
}